// Round 3
// baseline (404.919 us; speedup 1.0000x reference)
//
#include <hip/hip_runtime.h>

#define N_IMG 4
#define C_CH  256
#define FH    100
#define FW    152
#define CHW   (C_CH * FH * FW)
#define OUT_PER_ROI (C_CH * 7 * 7)   // 12544
#define SCALE 0.0625f
#define ROW_BYTES (FW * C_CH * 4)    // 155648
#define CH_BYTES  (C_CH * 4)         // 1024
#define LDS_STRIDE 29                // odd -> bank-conflict-free (2-way max)

// ---------------- Kernel 1: NCHW -> NHWC transpose of features ----------------
// float4 loads along x (FW=152 % 4 == 0): 1 KB per wave-instr.
__global__ __launch_bounds__(256) void transpose_nchw_nhwc(
    const float* __restrict__ in, float* __restrict__ out) {
  const int x0 = blockIdx.x * 32;
  const int y  = blockIdx.y;
  const int b  = blockIdx.z;
  __shared__ float tile[32][C_CH + 1];   // [x][ch], +1 pad
  const int chl = threadIdx.x & 31;
  const int xq  = threadIdx.x >> 5;      // 0..7, covers x0+4*xq .. +3
  const int x   = x0 + xq * 4;
  const bool inb = (x < FW);             // FW%4==0 -> whole float4 in/out of bounds
  const float4* src4 = (const float4*)in;
#pragma unroll
  for (int cc = 0; cc < C_CH; cc += 32) {
    const int ch = cc + chl;
    float4 v = make_float4(0.f, 0.f, 0.f, 0.f);
    if (inb) v = src4[((size_t)b * C_CH + ch) * (FH * FW / 4) + y * (FW / 4) + (x >> 2)];
    tile[xq * 4 + 0][ch] = v.x;
    tile[xq * 4 + 1][ch] = v.y;
    tile[xq * 4 + 2][ch] = v.z;
    tile[xq * 4 + 3][ch] = v.w;
  }
  __syncthreads();
  const int ch = threadIdx.x;
  float* dst = out + (((size_t)b * FH + y) * FW) * C_CH + ch;
#pragma unroll
  for (int xi = 0; xi < 32; ++xi) {
    const int xx = x0 + xi;
    if (xx < FW) dst[(size_t)xx * C_CH] = tile[xi][ch];
  }
}

// ---------------- Kernel 2: RoIAlign + 2x2 overlapping avg pool (NHWC) --------
// One block per ROI; 256 threads = 1 thread per channel.
// Chunked LDS staging (29 KB -> 5 blocks/CU, 20 waves/CU):
//   phase A: sample rows 0..4, pool rows 0..3 -> LDS, coalesced writeback
//   phase B: sample rows 5..7, pool rows 4..6 -> LDS, coalesced writeback
__global__ __launch_bounds__(256) void roialign_nhwc(
    const float* __restrict__ feat, const float* __restrict__ rois,
    const int* __restrict__ bids, float* __restrict__ out) {
  const int r = blockIdx.x;
  const int c = threadIdx.x;
  __shared__ float lds[C_CH * LDS_STRIDE];  // 29.0 KB

  const float x1 = rois[r * 4 + 0] * SCALE;
  const float y1 = rois[r * 4 + 1] * SCALE;
  const float x2 = rois[r * 4 + 2] * SCALE;
  const float y2 = rois[r * 4 + 3] * SCALE;
  const int   b  = bids[r];
  const float bw = fmaxf(x2 - x1 + 1.0f, 0.0f) * (1.0f / 7.0f);
  const float bh = fmaxf(y2 - y1 + 1.0f, 0.0f) * (1.0f / 7.0f);

  int   xoff[8];
  float wq0[8], wq1[8];
#pragma unroll
  for (int j = 0; j < 8; ++j) {
    const float w   = x1 + (float)j * bw;
    const float wsf = fminf(fmaxf(floorf(w), 0.0f), (float)(FW - 2));
    xoff[j] = (int)wsf * CH_BYTES;
    const float wr = w - wsf;
    const float mw = (w >= 0.0f && w < (float)FW) ? 1.0f : 0.0f;
    wq0[j] = (1.0f - wr) * mw;
    wq1[j] = wr * mw;
  }

  const char* fbb = (const char*)(feat + (size_t)b * CHW);
  const int   cb  = c * 4;
  float* outr = out + (size_t)r * OUT_PER_ROI;

  float prev[8], cur[8];

#define SAMPLE_ROW(i_)                                                        \
  {                                                                           \
    const float h   = y1 + (float)(i_)*bh;                                    \
    const float hsf = fminf(fmaxf(floorf(h), 0.0f), (float)(FH - 2));         \
    const float hr  = h - hsf;                                                \
    const float mh  = (h >= 0.0f && h < (float)FH) ? 1.0f : 0.0f;             \
    const float a0  = (1.0f - hr) * mh;                                       \
    const float a1  = hr * mh;                                                \
    const int   row0 = (int)hsf * ROW_BYTES + cb;                             \
    _Pragma("unroll") for (int j = 0; j < 8; ++j) {                           \
      const int o0 = row0 + xoff[j];                                          \
      const int o1 = o0 + ROW_BYTES;                                          \
      const float g00 = *(const float*)(fbb + o0);                            \
      const float g01 = *(const float*)(fbb + o0 + CH_BYTES);                 \
      const float g10 = *(const float*)(fbb + o1);                            \
      const float g11 = *(const float*)(fbb + o1 + CH_BYTES);                 \
      cur[j] = a0 * (g00 * wq0[j] + g01 * wq1[j]) +                           \
               a1 * (g10 * wq0[j] + g11 * wq1[j]);                            \
    }                                                                         \
  }

  // ---- Phase A: sample rows 0..4, pooled rows 0..3 ----
#pragma unroll 1
  for (int i = 0; i < 5; ++i) {
    SAMPLE_ROW(i);
    if (i > 0) {
      const int base = c * LDS_STRIDE + (i - 1) * 7;
#pragma unroll
      for (int j = 0; j < 7; ++j)
        lds[base + j] = (prev[j] + prev[j + 1] + cur[j] + cur[j + 1]) * 0.25f;
    }
#pragma unroll
    for (int j = 0; j < 8; ++j) prev[j] = cur[j];
  }
  __syncthreads();
  // Writeback rows 0..3: 28 floats/channel. Flat e -> (ch, p); coalesced scalar.
#pragma unroll
  for (int k = 0; k < 28; ++k) {
    const int e  = c + k * 256;           // 0 .. 7167
    const int cc = e / 28;
    const int p  = e - cc * 28;
    outr[cc * 49 + p] = lds[cc * LDS_STRIDE + p];
  }
  __syncthreads();

  // ---- Phase B: sample rows 5..7, pooled rows 4..6 ----
#pragma unroll 1
  for (int i = 5; i < 8; ++i) {
    SAMPLE_ROW(i);
    {
      const int base = c * LDS_STRIDE + (i - 5) * 7;
#pragma unroll
      for (int j = 0; j < 7; ++j)
        lds[base + j] = (prev[j] + prev[j + 1] + cur[j] + cur[j + 1]) * 0.25f;
    }
#pragma unroll
    for (int j = 0; j < 8; ++j) prev[j] = cur[j];
  }
  __syncthreads();
  // Writeback rows 4..6: 21 floats/channel.
#pragma unroll
  for (int k = 0; k < 21; ++k) {
    const int e  = c + k * 256;           // 0 .. 5375
    const int cc = e / 21;
    const int p  = e - cc * 21;
    outr[cc * 49 + 28 + p] = lds[cc * LDS_STRIDE + p];
  }
#undef SAMPLE_ROW
}

// ---------------- Host launch ----------------
extern "C" void kernel_launch(void* const* d_in, const int* in_sizes, int n_in,
                              void* d_out, int out_size, void* d_ws, size_t ws_size,
                              hipStream_t stream) {
  (void)n_in; (void)out_size; (void)ws_size;
  const float* features = (const float*)d_in[0];
  const float* rois     = (const float*)d_in[1];
  const int*   bids     = (const int*)d_in[2];
  float* out = (float*)d_out;
  const int R = in_sizes[1] / 4;  // 4000

  float* nhwc = (float*)d_ws;     // 62.3 MB needed; harness ws is ample
  dim3 tgrid((FW + 31) / 32, FH, N_IMG);  // (5, 100, 4)
  transpose_nchw_nhwc<<<tgrid, 256, 0, stream>>>(features, nhwc);
  roialign_nhwc<<<R, 256, 0, stream>>>(nhwc, rois, bids, out);
}

// Round 5
// 339.986 us; speedup vs baseline: 1.1910x; 1.1910x over previous
//
#include <hip/hip_runtime.h>

#define N_IMG 4
#define C_CH  256
#define FH    100
#define FW    152
#define CHW   (C_CH * FH * FW)
#define OUT_PER_ROI (C_CH * 7 * 7)   // 12544
#define SCALE 0.0625f
#define ROW_BYTES (FW * C_CH * 4)    // 155648
#define CH_BYTES  (C_CH * 4)         // 1024

typedef float nfloat4 __attribute__((ext_vector_type(4)));  // native vec for NT stores

// ---------------- Kernel 1: NCHW -> NHWC transpose of features ----------------
// float4 loads along x (FW=152 % 4 == 0): 1 KB per wave-instr.
__global__ __launch_bounds__(256) void transpose_nchw_nhwc(
    const float* __restrict__ in, float* __restrict__ out) {
  const int x0 = blockIdx.x * 32;
  const int y  = blockIdx.y;
  const int b  = blockIdx.z;
  __shared__ float tile[32][C_CH + 1];   // [x][ch], +1 pad
  const int chl = threadIdx.x & 31;
  const int xq  = threadIdx.x >> 5;      // 0..7, covers x0+4*xq .. +3
  const int x   = x0 + xq * 4;
  const bool inb = (x < FW);             // FW%4==0 -> whole float4 in/out of bounds
  const float4* src4 = (const float4*)in;
#pragma unroll
  for (int cc = 0; cc < C_CH; cc += 32) {
    const int ch = cc + chl;
    float4 v = make_float4(0.f, 0.f, 0.f, 0.f);
    if (inb) v = src4[((size_t)b * C_CH + ch) * (FH * FW / 4) + y * (FW / 4) + (x >> 2)];
    tile[xq * 4 + 0][ch] = v.x;
    tile[xq * 4 + 1][ch] = v.y;
    tile[xq * 4 + 2][ch] = v.z;
    tile[xq * 4 + 3][ch] = v.w;
  }
  __syncthreads();
  const int ch = threadIdx.x;
  float* dst = out + (((size_t)b * FH + y) * FW) * C_CH + ch;
#pragma unroll
  for (int xi = 0; xi < 32; ++xi) {
    const int xx = x0 + xi;
    if (xx < FW) dst[(size_t)xx * C_CH] = tile[xi][ch];
  }
}

// ---------------- Kernel 2: RoIAlign + 2x2 overlapping avg pool (NHWC) --------
// 512 threads per block, one block per ROI.
//   half 0 (waves 0-3): sample rows 0..4 -> pooled rows 0..3
//   half 1 (waves 4-7): sample rows 4..7 -> pooled rows 4..6  (row 4 resampled)
// 49 KB LDS staging -> 3 blocks/CU = 24 waves/CU for gather-latency hiding.
// Whole-ROI contiguous float4 writeback with non-temporal stores (keep L2 for
// the feature gathers; output is write-once).
__global__ __launch_bounds__(512) void roialign_nhwc(
    const float* __restrict__ feat, const float* __restrict__ rois,
    const int* __restrict__ bids, float* __restrict__ out) {
  const int r    = blockIdx.x;
  const int c    = threadIdx.x & 255;   // channel
  const int half = threadIdx.x >> 8;    // 0 or 1 (wave-uniform)
  __shared__ float lds[OUT_PER_ROI];    // 49 KB

  const float x1 = rois[r * 4 + 0] * SCALE;
  const float y1 = rois[r * 4 + 1] * SCALE;
  const float x2 = rois[r * 4 + 2] * SCALE;
  const float y2 = rois[r * 4 + 3] * SCALE;
  const int   b  = bids[r];
  const float bw = fmaxf(x2 - x1 + 1.0f, 0.0f) * (1.0f / 7.0f);
  const float bh = fmaxf(y2 - y1 + 1.0f, 0.0f) * (1.0f / 7.0f);

  // Per-column precompute: byte offset + masked bilinear column weights.
  int   xoff[8];
  float wq0[8], wq1[8];
#pragma unroll
  for (int j = 0; j < 8; ++j) {
    const float w   = x1 + (float)j * bw;
    const float wsf = fminf(fmaxf(floorf(w), 0.0f), (float)(FW - 2));
    xoff[j] = (int)wsf * CH_BYTES;
    const float wr = w - wsf;
    const float mw = (w >= 0.0f && w < (float)FW) ? 1.0f : 0.0f;
    wq0[j] = (1.0f - wr) * mw;
    wq1[j] = wr * mw;
  }

  const char* fbb = (const char*)(feat + (size_t)b * CHW);
  const int   cb  = c * 4;

  const int i0 = half ? 4 : 0;   // first sample row
  const int i1 = half ? 8 : 5;   // one past last sample row

  float prev[8], cur[8];
#pragma unroll 1
  for (int i = i0; i < i1; ++i) {
    const float h   = y1 + (float)i * bh;
    const float hsf = fminf(fmaxf(floorf(h), 0.0f), (float)(FH - 2));
    const float hr  = h - hsf;
    const float mh  = (h >= 0.0f && h < (float)FH) ? 1.0f : 0.0f;
    const float a0  = (1.0f - hr) * mh;
    const float a1  = hr * mh;
    const int   row0 = (int)hsf * ROW_BYTES + cb;
#pragma unroll
    for (int j = 0; j < 8; ++j) {
      const int o0 = row0 + xoff[j];
      const int o1 = o0 + ROW_BYTES;
      const float g00 = *(const float*)(fbb + o0);
      const float g01 = *(const float*)(fbb + o0 + CH_BYTES);
      const float g10 = *(const float*)(fbb + o1);
      const float g11 = *(const float*)(fbb + o1 + CH_BYTES);
      cur[j] = a0 * (g00 * wq0[j] + g01 * wq1[j]) +
               a1 * (g10 * wq0[j] + g11 * wq1[j]);
    }
    if (i > i0) {
      const int base = c * 49 + (i - 1) * 7;
#pragma unroll
      for (int j = 0; j < 7; ++j)
        lds[base + j] = (prev[j] + prev[j + 1] + cur[j] + cur[j + 1]) * 0.25f;
    }
#pragma unroll
    for (int j = 0; j < 8; ++j) prev[j] = cur[j];
  }

  __syncthreads();
  // Whole-ROI coalesced float4 writeback: 3136 float4s over 512 threads.
  nfloat4*       dst  = (nfloat4*)(out + (size_t)r * OUT_PER_ROI);
  const nfloat4* src4 = (const nfloat4*)lds;
#pragma unroll
  for (int k = 0; k < 7; ++k) {
    const int idx = threadIdx.x + k * 512;
    if (idx < (OUT_PER_ROI / 4)) __builtin_nontemporal_store(src4[idx], dst + idx);
  }
}

// ---------------- Host launch ----------------
extern "C" void kernel_launch(void* const* d_in, const int* in_sizes, int n_in,
                              void* d_out, int out_size, void* d_ws, size_t ws_size,
                              hipStream_t stream) {
  (void)n_in; (void)out_size; (void)ws_size;
  const float* features = (const float*)d_in[0];
  const float* rois     = (const float*)d_in[1];
  const int*   bids     = (const int*)d_in[2];
  float* out = (float*)d_out;
  const int R = in_sizes[1] / 4;  // 4000

  float* nhwc = (float*)d_ws;     // 62.3 MB needed; harness ws is ample
  dim3 tgrid((FW + 31) / 32, FH, N_IMG);  // (5, 100, 4)
  transpose_nchw_nhwc<<<tgrid, 256, 0, stream>>>(features, nhwc);
  roialign_nhwc<<<R, 512, 0, stream>>>(nhwc, rois, bids, out);
}